// Round 15
// baseline (7395.584 us; speedup 1.0000x reference)
//
#include <hip/hip_runtime.h>
#include <hip/hip_bf16.h>
#include <cstddef>

#define S_LEN 512
#define BATCH 64
#define HID 256
#define G3 768
#define SB (S_LEN*BATCH)
#define D2 512
#define L2E 1.44269504f

typedef unsigned short u16;
typedef _Float16 h2v __attribute__((ext_vector_type(2)));
typedef __attribute__((ext_vector_type(8))) short s16x8;
typedef __attribute__((ext_vector_type(4))) float f32x4;

__device__ __forceinline__ float bf2f(u16 u) {
    return __uint_as_float(((unsigned)u) << 16);
}
__device__ __forceinline__ u16 f2bf(float f) {
    unsigned u = __float_as_uint(f);
    unsigned r = (u + 0x7FFFu + ((u >> 16) & 1u)) >> 16;
    return (u16)r;
}
__device__ __forceinline__ u16 f2h_bits(float f) {
    _Float16 h = (_Float16)f;
    union { _Float16 h; u16 u; } cv; cv.h = h;
    return cv.u;
}
__device__ __forceinline__ h2v u2h(unsigned u) {
    union { unsigned u; h2v h; } cv; cv.u = u;
    return cv.h;
}
__device__ __forceinline__ float dot2f(unsigned w, unsigned h, float acc) {
#if __has_builtin(__builtin_amdgcn_fdot2)
    return __builtin_amdgcn_fdot2(u2h(w), u2h(h), acc, false);
#else
    h2v wv = u2h(w), hv = u2h(h);
    return acc + (float)wv.x * (float)hv.x + (float)wv.y * (float)hv.y;
#endif
}
__device__ __forceinline__ float fast_rcp(float x) {
#if __has_builtin(__builtin_amdgcn_rcpf)
    return __builtin_amdgcn_rcpf(x);
#else
    return 1.f / x;
#endif
}
__device__ __forceinline__ float fast_exp2(float x) {
#if __has_builtin(__builtin_amdgcn_exp2f)
    return __builtin_amdgcn_exp2f(x);
#else
    return __expf(x * 0.69314718f);
#endif
}
__device__ __forceinline__ void gload_lds16(const void* g, void* l) {
    __builtin_amdgcn_global_load_lds((const __attribute__((address_space(1))) void*)g,
                                     (__attribute__((address_space(3))) void*)l, 16, 0, 0);
}

// ---------- prep kernels ----------
__global__ void f32_to_bf16(const float* __restrict__ in, u16* __restrict__ out, long n) {
    long i = (long)blockIdx.x * 256 + threadIdx.x;
    if (i < n) out[i] = f2bf(in[i]);
}
// w_ih scaled: gate rows g<512 ×log2e, g>=512 ×2log2e (exp2 prescale)
__global__ void f32_to_bf16_gs(const float* __restrict__ in, u16* __restrict__ out,
                               long n, int K) {
    long i = (long)blockIdx.x * 256 + threadIdx.x;
    if (i >= n) return;
    int g = (int)((i / K) % 768);
    float sc = (g < 512) ? L2E : (2.f * L2E);
    out[i] = f2bf(in[i] * sc);
}
// w_hh f32 [12][768][256] -> packed half2 [12][128][768] u32, exp2-prescaled per gate
__global__ void pack_whh_f16_gs(const float* __restrict__ in, unsigned* __restrict__ out,
                                long total) {
    long i = (long)blockIdx.x * 256 + threadIdx.x;
    if (i >= total) return;
    long mat = i / (128L * G3);
    long rem = i - mat * (128L * G3);
    int k2 = (int)(rem / G3);
    int g  = (int)(rem - (long)k2 * G3);
    float sc = (g < 512) ? L2E : (2.f * L2E);
    const float* base = in + mat * (768L * 256) + (long)g * 256 + 2 * k2;
    unsigned lo = f2h_bits(base[0] * sc);
    unsigned hi = f2h_bits(base[1] * sc);
    out[i] = lo | (hi << 16);
}
// biasT[l][d][g]: g<512 -> (b_ih+b_hh)*log2e ; g>=512 -> b_ih*2log2e
__global__ void add_bias(const float* __restrict__ bih0, const float* __restrict__ bihl,
                         const float* __restrict__ bhh, float* __restrict__ outb) {
    int i = blockIdx.x * 256 + threadIdx.x;
    if (i >= 6 * 1536) return;
    int l = i / 1536, r = i - l * 1536;
    int g = r % 768;
    float bi = (l == 0) ? bih0[r] : bihl[(l - 1) * 1536 + r];
    outb[i] = (g < 512) ? (bi + bhh[i]) * L2E : bi * (2.f * L2E);
}

// ---------- input GEMM (MFMA) ----------
__global__ __launch_bounds__(256, 2) void gemm_mfma(
    const u16* __restrict__ A,
    const u16* __restrict__ Bt,
    const float* __restrict__ bias,
    u16* __restrict__ Cg,
    int K)
{
    int d = blockIdx.z;
    const u16* Bb = Bt + (size_t)d * 768 * K;
    const float* bi = bias + d * G3;
    u16* Cm = Cg + (size_t)d * SB * G3;

    int n0 = blockIdx.x * 128;
    int m0 = blockIdx.y * 128;
    int tid = threadIdx.x;
    int wave = tid >> 6, lane = tid & 63;
    int wm = wave >> 1, wn = wave & 1;

    __shared__ u16 Asm[128 * 32];
    __shared__ u16 Bsm[128 * 32];

    f32x4 acc[4][4] = {};

    for (int k0 = 0; k0 < K; k0 += 32) {
#pragma unroll
        for (int p = 0; p < 2; p++) {
            int c = p * 256 + wave * 64 + lane;
            int row = c >> 2, kc = c & 3;
            const u16* srcA = A + (size_t)(m0 + row) * K + k0 + kc * 8;
            const u16* srcB = Bb + (size_t)(n0 + row) * K + k0 + kc * 8;
            gload_lds16(srcA, &Asm[(p * 256 + wave * 64) * 8]);
            gload_lds16(srcB, &Bsm[(p * 256 + wave * 64) * 8]);
        }
        __syncthreads();

        s16x8 af[4], bfr[4];
#pragma unroll
        for (int i = 0; i < 4; i++) {
            int arow = wm * 64 + i * 16 + (lane & 15);
            af[i] = *reinterpret_cast<const s16x8*>(&Asm[arow * 32 + (lane >> 4) * 8]);
            int brow = wn * 64 + i * 16 + (lane & 15);
            bfr[i] = *reinterpret_cast<const s16x8*>(&Bsm[brow * 32 + (lane >> 4) * 8]);
        }
#pragma unroll
        for (int i = 0; i < 4; i++)
#pragma unroll
            for (int j = 0; j < 4; j++)
                acc[i][j] = __builtin_amdgcn_mfma_f32_16x16x32_bf16(af[i], bfr[j], acc[i][j], 0, 0, 0);
        __syncthreads();
    }

    int lcol = lane & 15, lrow4 = (lane >> 4) * 4;
#pragma unroll
    for (int i = 0; i < 4; i++) {
#pragma unroll
        for (int j = 0; j < 4; j++) {
            int n = n0 + wn * 64 + j * 16 + lcol;
            float bv = bi[n];
#pragma unroll
            for (int q = 0; q < 4; q++) {
                int m = m0 + wm * 64 + i * 16 + lrow4 + q;
                Cm[(size_t)m * G3 + n] = f2bf(acc[i][j][q] + bv);
            }
        }
    }
}

// ---------- recurrent scan (dot2, split-gate, 2 rows/block) ----------
// One block per (row PAIR, direction); 768 threads; thread owns gate tid for
// BOTH rows b0,b0+1 — each streamed weight register feeds 2 dot2, halving the
// per-step L2 weight traffic that bounds the R9 structure. Broadcast LDS h
// (conflict-free, proven). Two barriers/step as in R9.
__global__ __launch_bounds__(768, 3) void gru_scan(
    const unsigned* __restrict__ wpack,  // [12][128][768] u32 (half2 pairs), prescaled
    const float* __restrict__ bhh,       // [6][2][768] f32 raw
    const u16* __restrict__ gi,          // [2][SB][768] bf16 prescaled, r/z b_hh folded
    const float* __restrict__ h0,        // [12][64][256] f32
    u16* __restrict__ outc,              // [SB][512] bf16 (scratch on last layer)
    float* __restrict__ finals,          // [12][64][256] f32
    int layer)
{
    int b0 = blockIdx.x * 2;
    int d = blockIdx.y;
    int tid = threadIdx.x;

    int ld = layer * 2 + d;
    const unsigned* Wp = wpack + (size_t)ld * 128 * G3 + tid;
    const u16* gid = gi + (size_t)d * SB * G3;

    __shared__ float rz_s[2][512];                 // [row][r:0-255|z:256-511]
    __shared__ alignas(16) _Float16 h16A[HID];
    __shared__ alignas(16) _Float16 h16B[HID];
    __shared__ u16 gi_s[2][2][G3];                 // [par][row][g]

    unsigned wpk[128];
#pragma unroll
    for (int k = 0; k < 128; k++) wpk[k] = Wp[(size_t)k * G3];

    int gate = tid >> 8;          // 0=r, 1=z, 2=n
    int j = tid & 255;

    float hregA = 0.f, hregB = 0.f, bhn = 0.f;
    if (gate == 2) {
        hregA = h0[(size_t)ld * BATCH * HID + (b0 + 0) * HID + j];
        hregB = h0[(size_t)ld * BATCH * HID + (b0 + 1) * HID + j];
        bhn = bhh[(size_t)ld * G3 + 512 + j] * (2.f * L2E);
        h16A[j] = (_Float16)hregA;
        h16B[j] = (_Float16)hregB;
    }
    {
        int s0 = d ? (S_LEN - 1) : 0;
        gi_s[0][0][tid] = gid[((size_t)s0 * BATCH + b0) * G3 + tid];
        gi_s[0][1][tid] = gid[((size_t)s0 * BATCH + b0 + 1) * G3 + tid];
    }
    __syncthreads();

    for (int t = 0; t < S_LEN; t++) {
        int s = d ? (S_LEN - 1 - t) : t;
        // prefetch next step's gi for both rows
        u16 gnA = 0, gnB = 0;
        if (t + 1 < S_LEN) {
            int sn = d ? (s - 1) : (s + 1);
            gnA = gid[((size_t)sn * BATCH + b0) * G3 + tid];
            gnB = gid[((size_t)sn * BATCH + b0 + 1) * G3 + tid];
        }
        // dual-row dot: each weight reg used twice (halves L2 weight stream)
        float accA = 0.f, accB = 0.f;
        const uint4* hpA = reinterpret_cast<const uint4*>(h16A);
        const uint4* hpB = reinterpret_cast<const uint4*>(h16B);
#pragma unroll
        for (int k = 0; k < 32; k++) {
            uint4 qA = hpA[k];
            uint4 qB = hpB[k];
            unsigned w0 = wpk[4 * k + 0], w1 = wpk[4 * k + 1];
            unsigned w2 = wpk[4 * k + 2], w3 = wpk[4 * k + 3];
            accA = dot2f(w0, qA.x, accA);  accB = dot2f(w0, qB.x, accB);
            accA = dot2f(w1, qA.y, accA);  accB = dot2f(w1, qB.y, accB);
            accA = dot2f(w2, qA.z, accA);  accB = dot2f(w2, qB.z, accB);
            accA = dot2f(w3, qA.w, accA);  accB = dot2f(w3, qB.w, accB);
        }
        int par = t & 1;
        float givA = bf2f(gi_s[par][0][tid]);
        float givB = bf2f(gi_s[par][1][tid]);
        gi_s[par ^ 1][0][tid] = gnA;
        gi_s[par ^ 1][1][tid] = gnB;
        // phase A: r/z lanes finish their gate for both rows
        if (gate < 2) {
            rz_s[0][tid] = fast_rcp(1.f + fast_exp2(-(givA + accA)));
            rz_s[1][tid] = fast_rcp(1.f + fast_exp2(-(givB + accB)));
        }
        __syncthreads();
        // phase B: n-lanes finish n-gate + h update for both rows
        if (gate == 2) {
            float rA = rz_s[0][j], zA = rz_s[0][256 + j];
            float rB = rz_s[1][j], zB = rz_s[1][256 + j];
            float xnA = givA + rA * (accA + bhn);
            float nA = 1.f - 2.f * fast_rcp(fast_exp2(xnA) + 1.f);
            float hnA = nA + zA * (hregA - nA);
            hregA = hnA; h16A[j] = (_Float16)hnA;
            float xnB = givB + rB * (accB + bhn);
            float nB = 1.f - 2.f * fast_rcp(fast_exp2(xnB) + 1.f);
            float hnB = nB + zB * (hregB - nB);
            hregB = hnB; h16B[j] = (_Float16)hnB;
            size_t ob = ((size_t)s * BATCH + b0) * D2 + d * HID + j;
            outc[ob] = f2bf(hnA);
            outc[ob + D2] = f2bf(hnB);
        }
        __syncthreads();
    }
    if (gate == 2) {
        finals[(size_t)ld * BATCH * HID + (b0 + 0) * HID + j] = hregA;
        finals[(size_t)ld * BATCH * HID + (b0 + 1) * HID + j] = hregB;
    }
}

extern "C" void kernel_launch(void* const* d_in, const int* in_sizes, int n_in,
                              void* d_out, int out_size, void* d_ws, size_t ws_size,
                              hipStream_t stream) {
    const float* x     = (const float*)d_in[0];
    const float* h0    = (const float*)d_in[1];
    const float* w_ih0 = (const float*)d_in[2];
    const float* b_ih0 = (const float*)d_in[3];
    const float* w_ih  = (const float*)d_in[4];
    const float* b_ih  = (const float*)d_in[5];
    const float* w_hh  = (const float*)d_in[6];
    const float* b_hh  = (const float*)d_in[7];
    float* out = (float*)d_out;

    char* ws = (char*)d_ws;
    // wpack u32 [12][128][768]    @ 0           4,718,592
    // wbf0  bf16 [2][768][128]    @ 4,718,592     393,216
    // wbfl  bf16 [5][2][768][512] @ 5,111,808   7,864,320
    // biasT f32 [6][2][768]       @ 12,976,128     36,864
    // gi    bf16 [2][SB][768]     @ 13,012,992 100,663,296
    // curA  bf16 [SB][512]        @ 113,676,288 33,554,432
    // curB  bf16 [SB][512]        @ 147,230,720 33,554,432
    unsigned* wpack = (unsigned*)(ws + 0);
    u16* wbf0  = (u16*)(ws + 4718592);
    u16* wbfl  = (u16*)(ws + 5111808);
    float* biasT = (float*)(ws + 12976128);
    u16* gi    = (u16*)(ws + 13012992);
    u16* curA  = (u16*)(ws + 113676288);
    u16* curB  = (u16*)(ws + 147230720);

    pack_whh_f16_gs<<<(1179648 + 255) / 256, 256, 0, stream>>>(w_hh, wpack, 1179648L);
    f32_to_bf16_gs<<<(196608 + 255) / 256, 256, 0, stream>>>(w_ih0, wbf0, 196608L, 128);
    f32_to_bf16_gs<<<(3932160 + 255) / 256, 256, 0, stream>>>(w_ih, wbfl, 3932160L, 512);
    f32_to_bf16<<<(4194304 + 255) / 256, 256, 0, stream>>>(x, curA, 4194304L);
    add_bias<<<(9216 + 255) / 256, 256, 0, stream>>>(b_ih0, b_ih, b_hh, biasT);

    u16* cin = curA;
    u16* cout_ = curB;
    for (int l = 0; l < 6; l++) {
        int K = l ? 512 : 128;
        const u16* wt = l ? (wbfl + (size_t)(l - 1) * 2 * 768 * 512) : wbf0;
        const float* bi = biasT + (size_t)l * 1536;
        dim3 g(6, 256, 2);
        gemm_mfma<<<g, 256, 0, stream>>>(cin, wt, bi, gi, K);
        gru_scan<<<dim3(32, 2), 768, 0, stream>>>(wpack, b_hh, gi, h0,
                                                  cout_, out, l);
        u16* tmp = cin; cin = cout_; cout_ = tmp;
    }
}

// Round 16
// 4025.921 us; speedup vs baseline: 1.8370x; 1.8370x over previous
//
#include <hip/hip_runtime.h>
#include <hip/hip_bf16.h>
#include <cstddef>

#define S_LEN 512
#define BATCH 64
#define HID 256
#define G3 768
#define SB (S_LEN*BATCH)
#define D2 512
#define L2E 1.44269504f

typedef unsigned short u16;
typedef _Float16 h2v __attribute__((ext_vector_type(2)));
typedef __attribute__((ext_vector_type(8))) short s16x8;
typedef __attribute__((ext_vector_type(4))) float f32x4;

__device__ __forceinline__ float bf2f(u16 u) {
    return __uint_as_float(((unsigned)u) << 16);
}
__device__ __forceinline__ u16 f2bf(float f) {
    unsigned u = __float_as_uint(f);
    unsigned r = (u + 0x7FFFu + ((u >> 16) & 1u)) >> 16;
    return (u16)r;
}
__device__ __forceinline__ u16 f2h_bits(float f) {
    _Float16 h = (_Float16)f;
    union { _Float16 h; u16 u; } cv; cv.h = h;
    return cv.u;
}
__device__ __forceinline__ h2v u2h(unsigned u) {
    union { unsigned u; h2v h; } cv; cv.u = u;
    return cv.h;
}
__device__ __forceinline__ float dot2f(unsigned w, unsigned h, float acc) {
#if __has_builtin(__builtin_amdgcn_fdot2)
    return __builtin_amdgcn_fdot2(u2h(w), u2h(h), acc, false);
#else
    h2v wv = u2h(w), hv = u2h(h);
    return acc + (float)wv.x * (float)hv.x + (float)wv.y * (float)hv.y;
#endif
}
__device__ __forceinline__ float fast_rcp(float x) {
#if __has_builtin(__builtin_amdgcn_rcpf)
    return __builtin_amdgcn_rcpf(x);
#else
    return 1.f / x;
#endif
}
__device__ __forceinline__ float fast_exp2(float x) {
#if __has_builtin(__builtin_amdgcn_exp2f)
    return __builtin_amdgcn_exp2f(x);
#else
    return __expf(x * 0.69314718f);
#endif
}
__device__ __forceinline__ void gload_lds16(const void* g, void* l) {
    __builtin_amdgcn_global_load_lds((const __attribute__((address_space(1))) void*)g,
                                     (__attribute__((address_space(3))) void*)l, 16, 0, 0);
}

// ---------- prep kernels ----------
__global__ void f32_to_bf16(const float* __restrict__ in, u16* __restrict__ out, long n) {
    long i = (long)blockIdx.x * 256 + threadIdx.x;
    if (i < n) out[i] = f2bf(in[i]);
}
// w_ih scaled: gate rows g<512 ×log2e, g>=512 ×2log2e (exp2 prescale)
__global__ void f32_to_bf16_gs(const float* __restrict__ in, u16* __restrict__ out,
                               long n, int K) {
    long i = (long)blockIdx.x * 256 + threadIdx.x;
    if (i >= n) return;
    int g = (int)((i / K) % 768);
    float sc = (g < 512) ? L2E : (2.f * L2E);
    out[i] = f2bf(in[i] * sc);
}
// LANE-MAJOR weight pack: wpack[mat][g][k2], k2 in [0,128) — each gate's 128 u32
// contiguous (512 B) so the scan streams them as 32 x dwordx4 instead of 128 x dword.
// u32 = half2(W[g][2k2], W[g][2k2+1]) * gate_scale (exp2 prescale).
__global__ void pack_whh_lane(const float* __restrict__ in, unsigned* __restrict__ out,
                              long total) {
    long i = (long)blockIdx.x * 256 + threadIdx.x;
    if (i >= total) return;
    long mat = i / (768L * 128);
    long rem = i - mat * (768L * 128);
    int g  = (int)(rem / 128);
    int k2 = (int)(rem - (long)g * 128);
    float sc = (g < 512) ? L2E : (2.f * L2E);
    const float* base = in + mat * (768L * 256) + (long)g * 256 + 2 * k2;
    unsigned lo = f2h_bits(base[0] * sc);
    unsigned hi = f2h_bits(base[1] * sc);
    out[i] = lo | (hi << 16);
}
// biasT[l][d][g]: g<512 -> (b_ih+b_hh)*log2e ; g>=512 -> b_ih*2log2e
__global__ void add_bias(const float* __restrict__ bih0, const float* __restrict__ bihl,
                         const float* __restrict__ bhh, float* __restrict__ outb) {
    int i = blockIdx.x * 256 + threadIdx.x;
    if (i >= 6 * 1536) return;
    int l = i / 1536, r = i - l * 1536;
    int g = r % 768;
    float bi = (l == 0) ? bih0[r] : bihl[(l - 1) * 1536 + r];
    outb[i] = (g < 512) ? (bi + bhh[i]) * L2E : bi * (2.f * L2E);
}

// ---------- input GEMM (MFMA) ----------
__global__ __launch_bounds__(256, 2) void gemm_mfma(
    const u16* __restrict__ A,
    const u16* __restrict__ Bt,
    const float* __restrict__ bias,
    u16* __restrict__ Cg,
    int K)
{
    int d = blockIdx.z;
    const u16* Bb = Bt + (size_t)d * 768 * K;
    const float* bi = bias + d * G3;
    u16* Cm = Cg + (size_t)d * SB * G3;

    int n0 = blockIdx.x * 128;
    int m0 = blockIdx.y * 128;
    int tid = threadIdx.x;
    int wave = tid >> 6, lane = tid & 63;
    int wm = wave >> 1, wn = wave & 1;

    __shared__ u16 Asm[128 * 32];
    __shared__ u16 Bsm[128 * 32];

    f32x4 acc[4][4] = {};

    for (int k0 = 0; k0 < K; k0 += 32) {
#pragma unroll
        for (int p = 0; p < 2; p++) {
            int c = p * 256 + wave * 64 + lane;
            int row = c >> 2, kc = c & 3;
            const u16* srcA = A + (size_t)(m0 + row) * K + k0 + kc * 8;
            const u16* srcB = Bb + (size_t)(n0 + row) * K + k0 + kc * 8;
            gload_lds16(srcA, &Asm[(p * 256 + wave * 64) * 8]);
            gload_lds16(srcB, &Bsm[(p * 256 + wave * 64) * 8]);
        }
        __syncthreads();

        s16x8 af[4], bfr[4];
#pragma unroll
        for (int i = 0; i < 4; i++) {
            int arow = wm * 64 + i * 16 + (lane & 15);
            af[i] = *reinterpret_cast<const s16x8*>(&Asm[arow * 32 + (lane >> 4) * 8]);
            int brow = wn * 64 + i * 16 + (lane & 15);
            bfr[i] = *reinterpret_cast<const s16x8*>(&Bsm[brow * 32 + (lane >> 4) * 8]);
        }
#pragma unroll
        for (int i = 0; i < 4; i++)
#pragma unroll
            for (int j = 0; j < 4; j++)
                acc[i][j] = __builtin_amdgcn_mfma_f32_16x16x32_bf16(af[i], bfr[j], acc[i][j], 0, 0, 0);
        __syncthreads();
    }

    int lcol = lane & 15, lrow4 = (lane >> 4) * 4;
#pragma unroll
    for (int i = 0; i < 4; i++) {
#pragma unroll
        for (int j = 0; j < 4; j++) {
            int n = n0 + wn * 64 + j * 16 + lcol;
            float bv = bi[n];
#pragma unroll
            for (int q = 0; q < 4; q++) {
                int m = m0 + wm * 64 + i * 16 + lrow4 + q;
                Cm[(size_t)m * G3 + n] = f2bf(acc[i][j][q] + bv);
            }
        }
    }
}

// ---------- recurrent scan (R9 structure + lane-major dwordx4 weight stream) ----------
// One block per (batch row, direction); 768 threads; lane tid owns gate tid.
// Weight stream: 32 x dwordx4 per lane per step (contiguous 512 B) vs R9's
// 128 x dword — 4x fewer VMEM instructions, the diagnosed issue-bound term.
__global__ __launch_bounds__(768, 3) void gru_scan(
    const unsigned* __restrict__ wpack,  // [12][768][128] u32 lane-major, prescaled
    const float* __restrict__ bhh,       // [6][2][768] f32 raw
    const u16* __restrict__ gi,          // [2][SB][768] bf16 prescaled, r/z b_hh folded
    const float* __restrict__ h0,        // [12][64][256] f32
    u16* __restrict__ outc,              // [SB][512] bf16 (scratch on last layer)
    float* __restrict__ finals,          // [12][64][256] f32
    int layer)
{
    int b = blockIdx.x;
    int d = blockIdx.y;
    int tid = threadIdx.x;

    int ld = layer * 2 + d;
    const uint4* wp4 = reinterpret_cast<const uint4*>(
        wpack + (size_t)ld * G3 * 128 + (size_t)tid * 128);
    const u16* gid = gi + (size_t)d * SB * G3;

    __shared__ float rz_s[512];                    // r[0:256], z[256:512]
    __shared__ alignas(16) _Float16 h16_s[HID];
    __shared__ u16 gi_s[2][G3];

    int gate = tid >> 8;          // 0=r, 1=z, 2=n
    int j = tid & 255;

    float hreg = 0.f, bhn = 0.f;
    if (gate == 2) {
        hreg = h0[(size_t)ld * BATCH * HID + b * HID + j];
        bhn = bhh[(size_t)ld * G3 + 512 + j] * (2.f * L2E);
        h16_s[j] = (_Float16)hreg;
    }
    {
        int s0 = d ? (S_LEN - 1) : 0;
        gi_s[0][tid] = gid[((size_t)s0 * BATCH + b) * G3 + tid];
    }
    __syncthreads();

    for (int t = 0; t < S_LEN; t++) {
        int s = d ? (S_LEN - 1 - t) : t;
        // prefetch next step's gi
        u16 ginext = 0;
        if (t + 1 < S_LEN) {
            int sn = d ? (s - 1) : (s + 1);
            ginext = gid[((size_t)sn * BATCH + b) * G3 + tid];
        }
        // dot: 32 x (dwordx4 weight load + ds_read_b128 h) -> 128 dot2
        float acc = 0.f;
        const uint4* hp = reinterpret_cast<const uint4*>(h16_s);
#pragma unroll
        for (int k = 0; k < 32; k++) {
            uint4 wq = wp4[k];
            uint4 q = hp[k];
            acc = dot2f(wq.x, q.x, acc);
            acc = dot2f(wq.y, q.y, acc);
            acc = dot2f(wq.z, q.z, acc);
            acc = dot2f(wq.w, q.w, acc);
        }
        float giv = bf2f(gi_s[t & 1][tid]);
        gi_s[(t + 1) & 1][tid] = ginext;
        // phase A: r/z lanes finish their gate from OWN acc
        if (gate < 2)
            rz_s[tid] = fast_rcp(1.f + fast_exp2(-(giv + acc)));
        __syncthreads();
        // phase B: n-lanes finish n-gate + h update
        if (gate == 2) {
            float r = rz_s[j];
            float z = rz_s[256 + j];
            float xn2 = giv + r * (acc + bhn);              // = 2*log2e * xn
            float n = 1.f - 2.f * fast_rcp(fast_exp2(xn2) + 1.f);
            float hn = n + z * (hreg - n);
            hreg = hn;
            h16_s[j] = (_Float16)hn;
            outc[((size_t)s * BATCH + b) * D2 + d * HID + j] = f2bf(hn);
        }
        __syncthreads();
    }
    if (gate == 2)
        finals[(size_t)ld * BATCH * HID + b * HID + j] = hreg;
}

extern "C" void kernel_launch(void* const* d_in, const int* in_sizes, int n_in,
                              void* d_out, int out_size, void* d_ws, size_t ws_size,
                              hipStream_t stream) {
    const float* x     = (const float*)d_in[0];
    const float* h0    = (const float*)d_in[1];
    const float* w_ih0 = (const float*)d_in[2];
    const float* b_ih0 = (const float*)d_in[3];
    const float* w_ih  = (const float*)d_in[4];
    const float* b_ih  = (const float*)d_in[5];
    const float* w_hh  = (const float*)d_in[6];
    const float* b_hh  = (const float*)d_in[7];
    float* out = (float*)d_out;

    char* ws = (char*)d_ws;
    // wpack u32 [12][768][128]    @ 0           4,718,592
    // wbf0  bf16 [2][768][128]    @ 4,718,592     393,216
    // wbfl  bf16 [5][2][768][512] @ 5,111,808   7,864,320
    // biasT f32 [6][2][768]       @ 12,976,128     36,864
    // gi    bf16 [2][SB][768]     @ 13,012,992 100,663,296
    // curA  bf16 [SB][512]        @ 113,676,288 33,554,432
    // curB  bf16 [SB][512]        @ 147,230,720 33,554,432
    unsigned* wpack = (unsigned*)(ws + 0);
    u16* wbf0  = (u16*)(ws + 4718592);
    u16* wbfl  = (u16*)(ws + 5111808);
    float* biasT = (float*)(ws + 12976128);
    u16* gi    = (u16*)(ws + 13012992);
    u16* curA  = (u16*)(ws + 113676288);
    u16* curB  = (u16*)(ws + 147230720);

    pack_whh_lane<<<(1179648 + 255) / 256, 256, 0, stream>>>(w_hh, wpack, 1179648L);
    f32_to_bf16_gs<<<(196608 + 255) / 256, 256, 0, stream>>>(w_ih0, wbf0, 196608L, 128);
    f32_to_bf16_gs<<<(3932160 + 255) / 256, 256, 0, stream>>>(w_ih, wbfl, 3932160L, 512);
    f32_to_bf16<<<(4194304 + 255) / 256, 256, 0, stream>>>(x, curA, 4194304L);
    add_bias<<<(9216 + 255) / 256, 256, 0, stream>>>(b_ih0, b_ih, b_hh, biasT);

    u16* cin = curA;
    u16* cout_ = curB;
    for (int l = 0; l < 6; l++) {
        int K = l ? 512 : 128;
        const u16* wt = l ? (wbfl + (size_t)(l - 1) * 2 * 768 * 512) : wbf0;
        const float* bi = biasT + (size_t)l * 1536;
        dim3 g(6, 256, 2);
        gemm_mfma<<<g, 256, 0, stream>>>(cin, wt, bi, gi, K);
        gru_scan<<<dim3(64, 2), 768, 0, stream>>>(wpack, b_hh, gi, h0,
                                                  cout_, out, l);
        u16* tmp = cin; cin = cout_; cout_ = tmp;
    }
}